// Round 3
// baseline (310.303 us; speedup 1.0000x reference)
//
#include <hip/hip_runtime.h>

#define NEXP 5
#define MAXF 128
#define NOUT 512

// ws layout (ints): [0..4]=cnt, [8..12]=scatter cursors, [64..64+n)=perm
// then (256-byte aligned) Wt2: float[5][32][512][4]  (W transposed, k-packed by 4)

// blocks [0, nb): per-block LDS histogram of feat -> 5 global atomics/block
// blocks [nb, nb+320): transpose W[e][o][k] -> Wt2[e][k/4][o][k%4]
__global__ void misl_prep(const int* __restrict__ feat, const float* __restrict__ w,
                          int* __restrict__ ws, float* __restrict__ wt2, int n, int nb) {
    if ((int)blockIdx.x < nb) {
        __shared__ int lcnt[NEXP];
        const int tid = threadIdx.x;
        if (tid < NEXP) lcnt[tid] = 0;
        __syncthreads();
        const int t = blockIdx.x * 256 + tid;
        if (t < n) {
            const int e = __ffs(feat[t]) - 4;   // 8->0,16->1,32->2,64->3,128->4
            atomicAdd(&lcnt[e], 1);
        }
        __syncthreads();
        if (tid < NEXP) atomicAdd(&ws[tid], lcnt[tid]);
    } else {
        const int idx = (blockIdx.x - nb) * 256 + threadIdx.x;  // 5*32*512 = 81920
        const int o  = idx & 511;
        const int kb = (idx >> 9) & 31;
        const int e  = idx >> 14;
        const float4 v = *(const float4*)(w + ((size_t)(e * NOUT + o)) * MAXF + kb * 4);
        *(float4*)(wt2 + ((size_t)((e * 32 + kb) * NOUT + o)) * 4) = v;  // coalesced store
    }
}

// rank via LDS atomics; per-expert block base via one global atomic per block.
// segment starts computed locally from cnt[] (hist complete).
__global__ void misl_scatter(const int* __restrict__ feat, int* __restrict__ ws, int n) {
    __shared__ int lcnt[NEXP];
    __shared__ int lbase[NEXP];
    const int tid = threadIdx.x;
    if (tid < NEXP) lcnt[tid] = 0;
    __syncthreads();
    const int t = blockIdx.x * 256 + tid;
    int e = 0, r = 0;
    if (t < n) {
        e = __ffs(feat[t]) - 4;
        r = atomicAdd(&lcnt[e], 1);
    }
    __syncthreads();
    if (tid < NEXP) {
        int s = 0;
        for (int i = 0; i < tid; ++i) s += ws[i];
        lbase[tid] = s + atomicAdd(&ws[8 + tid], lcnt[tid]);
    }
    __syncthreads();
    if (t < n) ws[64 + lbase[e] + r] = t;
}

// lane = output column; tokens iterated with wave-uniform index -> x via SMEM
// scalar loads, W via coalesced per-lane float4 (reused over 16 tokens).
template <int K, int TC>
__device__ __forceinline__ void run_group(
    const float* __restrict__ x, const float* __restrict__ wt2e, float bias,
    const int* __restrict__ tokp, int tcnt, int o, float* __restrict__ out) {
    constexpr int KC = (K < 32) ? K : 32;   // k-chunk size (floats)
    for (int t0 = 0; t0 < tcnt; t0 += TC) {
        float acc[TC];
        #pragma unroll
        for (int t = 0; t < TC; ++t) acc[t] = bias;
        #pragma unroll
        for (int k0 = 0; k0 < K; k0 += KC) {
            float4 wreg[KC / 4];
            #pragma unroll
            for (int c = 0; c < KC / 4; ++c)
                wreg[c] = *(const float4*)(wt2e + (size_t)(((k0 >> 2) + c) * NOUT + o) * 4);
            #pragma unroll
            for (int t = 0; t < TC; ++t) {
                const int ti = t0 + t;
                const int tok = tokp[ti < tcnt ? ti : tcnt - 1];  // uniform clamp
                const float4* xr = (const float4*)(x + (size_t)tok * MAXF + k0);
                float s = acc[t];
                #pragma unroll
                for (int c = 0; c < KC / 4; ++c) {
                    const float4 xv = xr[c];
                    s += xv.x * wreg[c].x;
                    s += xv.y * wreg[c].y;
                    s += xv.z * wreg[c].z;
                    s += xv.w * wreg[c].w;
                }
                acc[t] = s;
            }
        }
        #pragma unroll
        for (int t = 0; t < TC; ++t) {
            const int ti = t0 + t;
            if (ti < tcnt) out[(size_t)tokp[ti] * NOUT + o] = acc[t];
        }
    }
}

__global__ __launch_bounds__(256) void misl_main(
    const float* __restrict__ x, const float* __restrict__ wt2,
    const float* __restrict__ b, const int* __restrict__ ws,
    float* __restrict__ out) {
    const int g  = blockIdx.x >> 1;
    const int ob = blockIdx.x & 1;

    // local prefix over the 5 counts; group ordering: heavy experts first (e=4..0)
    const int c0 = ws[0], c1 = ws[1], c2 = ws[2], c3 = ws[3], c4 = ws[4];
    const int cnts[NEXP] = {c0, c1, c2, c3, c4};
    const int segs[NEXP] = {0, c0, c0 + c1, c0 + c1 + c2, c0 + c1 + c2 + c3};
    int gb[NEXP + 1];
    gb[0] = 0;
    #pragma unroll
    for (int j = 0; j < NEXP; ++j) gb[j + 1] = gb[j] + ((cnts[4 - j] + 63) >> 6);
    if (g >= gb[NEXP]) return;

    int j = 0;
    #pragma unroll
    for (int i = 0; i < NEXP - 1; ++i)
        if (g >= gb[i + 1]) j = i + 1;
    const int e   = 4 - j;
    const int lg  = g - gb[j];
    int tcnt = cnts[e] - lg * 64;
    if (tcnt > 64) tcnt = 64;

    const int o = ob * 256 + threadIdx.x;            // 0..511
    const int* tokp = ws + 64 + segs[e] + lg * 64;
    const float bias = b[e * NOUT + o];
    const float* wt2e = wt2 + (size_t)e * 32 * NOUT * 4;

    switch (e) {
        case 0: run_group<8,   16>(x, wt2e, bias, tokp, tcnt, o, out); break;
        case 1: run_group<16,  16>(x, wt2e, bias, tokp, tcnt, o, out); break;
        case 2: run_group<32,  16>(x, wt2e, bias, tokp, tcnt, o, out); break;
        case 3: run_group<64,  16>(x, wt2e, bias, tokp, tcnt, o, out); break;
        case 4: run_group<128, 16>(x, wt2e, bias, tokp, tcnt, o, out); break;
    }
}

extern "C" void kernel_launch(void* const* d_in, const int* in_sizes, int n_in,
                              void* d_out, int out_size, void* d_ws, size_t ws_size,
                              hipStream_t stream) {
    const float* x    = (const float*)d_in[0];
    const int*   feat = (const int*)d_in[1];
    const float* w    = (const float*)d_in[2];
    const float* b    = (const float*)d_in[3];
    float* out = (float*)d_out;
    int*   ws  = (int*)d_ws;

    const int n  = in_sizes[1];                       // tokens = 32768
    const int nb = (n + 255) / 256;

    const size_t wt2_off = (((size_t)(64 + n) * 4) + 255) & ~(size_t)255;
    float* wt2 = (float*)((char*)d_ws + wt2_off);     // 1.25 MB

    hipMemsetAsync(ws, 0, 64 * sizeof(int), stream);
    misl_prep<<<nb + 320, 256, 0, stream>>>(feat, w, ws, wt2, n, nb);
    misl_scatter<<<nb, 256, 0, stream>>>(feat, ws, n);

    const int gmax = (n + 63) / 64 + NEXP;            // padded-group upper bound
    misl_main<<<gmax * 2, 256, 0, stream>>>(x, wt2, b, ws, out);
}

// Round 4
// 240.704 us; speedup vs baseline: 1.2891x; 1.2891x over previous
//
#include <hip/hip_runtime.h>

#define NEXP 5
#define MAXF 128
#define NOUT 512
#define NBMAX 256
#define PERMOFF (64 + NBMAX * NEXP)   // 1344 ints

// ws int layout:
//   [0..4]   cnt[e]   (written by scatter blk 0)
//   [8..12]  seg[e]   (segment starts, scatter blk 0)
//   [64 .. 64+nb*5)   per-block hist partials hist[b*5+e]   (prep, no atomics)
//   [PERMOFF .. PERMOFF+n)  perm (sorted token ids)
// then 256B-aligned Wt2: float[5][32][512][4] (k-packed-by-4 transpose of W)

__global__ __launch_bounds__(256) void misl_prep(
    const int* __restrict__ feat, const float* __restrict__ w,
    int* __restrict__ ws, float* __restrict__ wt2, int n, int nb) {
    if ((int)blockIdx.x < nb) {
        __shared__ int lcnt[NEXP];
        const int tid = threadIdx.x;
        if (tid < NEXP) lcnt[tid] = 0;
        __syncthreads();
        const int t = blockIdx.x * 256 + tid;
        if (t < n) { const int e = __ffs(feat[t]) - 4; atomicAdd(&lcnt[e], 1); }
        __syncthreads();
        if (tid < NEXP) ws[64 + blockIdx.x * NEXP + tid] = lcnt[tid];
    } else {
        const int idx = ((int)blockIdx.x - nb) * 256 + threadIdx.x;  // 81920 total
        const int o = idx & 511, kb = (idx >> 9) & 31, e = idx >> 14;
        const float4 v = *(const float4*)(w + (size_t)(e * NOUT + o) * MAXF + kb * 4);
        *(float4*)(wt2 + (size_t)((e * 32 + kb) * NOUT + o) * 4) = v;
    }
}

// Deterministic global offsets from the partial-hist table; only LDS atomics.
__global__ __launch_bounds__(256) void misl_scatter(
    const int* __restrict__ feat, int* __restrict__ ws, int n, int nb) {
    __shared__ int ph[NBMAX * NEXP];
    __shared__ int lcnt[NEXP], lbase[NEXP], ltot[NEXP];
    const int tid = threadIdx.x;
    for (int i = tid; i < nb * NEXP; i += 256) ph[i] = ws[64 + i];
    if (tid < NEXP) lcnt[tid] = 0;
    __syncthreads();
    if (tid < NEXP) {
        int tot = 0, pre = 0;
        for (int bb = 0; bb < nb; ++bb) {
            if (bb == (int)blockIdx.x) pre = tot;
            tot += ph[bb * NEXP + tid];
        }
        ltot[tid] = tot;
        lbase[tid] = pre;
    }
    __syncthreads();
    if (tid < NEXP) {
        int seg = 0;
        for (int e = 0; e < tid; ++e) seg += ltot[e];
        lbase[tid] += seg;
        if (blockIdx.x == 0) { ws[tid] = ltot[tid]; ws[8 + tid] = seg; }
    }
    __syncthreads();
    const int t = blockIdx.x * 256 + tid;
    if (t < n) {
        const int e = __ffs(feat[t]) - 4;
        const int r = atomicAdd(&lcnt[e], 1);
        ws[PERMOFF + lbase[e] + r] = t;
    }
}

// Block = 512 threads, one output column each. Tokens wave-uniform (SGPR base,
// broadcast x loads); W coalesced float4 from Wt2; out stores coalesced.
// Sub-chunk 16 tokens (acc[16]); k-chunks of <=32 floats (wreg <= 32 VGPRs).
template <int K>
__device__ __forceinline__ void run_group(
    const float* __restrict__ x, const float* __restrict__ wt2e, float bias,
    const int* __restrict__ tokp, int tcnt, int o, float* __restrict__ out) {
    constexpr int KC = (K < 32) ? K : 32;
    for (int t0 = 0; t0 < tcnt; t0 += 16) {
        int tok[16];
        #pragma unroll
        for (int t = 0; t < 16; ++t) {
            int ti = t0 + t;
            if (ti > tcnt - 1) ti = tcnt - 1;       // uniform clamp
            tok[t] = __builtin_amdgcn_readfirstlane(tokp[ti]);
        }
        float acc[16];
        #pragma unroll
        for (int t = 0; t < 16; ++t) acc[t] = bias;
        #pragma unroll 1
        for (int kc = 0; kc < K; kc += KC) {
            float4 wreg[KC / 4];
            #pragma unroll
            for (int kb = 0; kb < KC / 4; ++kb)
                wreg[kb] = *(const float4*)(wt2e + (size_t)(((kc >> 2) + kb) * NOUT + o) * 4);
            #pragma unroll
            for (int kb = 0; kb < KC / 4; ++kb) {
                const float4 wv = wreg[kb];
                #pragma unroll
                for (int t = 0; t < 16; ++t) {
                    const float4 xv = *(const float4*)(x + (size_t)tok[t] * MAXF + kc + kb * 4);
                    acc[t] += xv.x * wv.x + xv.y * wv.y + xv.z * wv.z + xv.w * wv.w;
                }
            }
        }
        #pragma unroll
        for (int t = 0; t < 16; ++t) {
            const int ti = t0 + t;
            if (ti < tcnt) out[(size_t)tok[t] * NOUT + o] = acc[t];
        }
    }
}

__global__ __launch_bounds__(512) void misl_main(
    const float* __restrict__ x, const float* __restrict__ wt2,
    const float* __restrict__ b, const int* __restrict__ ws,
    float* __restrict__ out) {
    const int g = blockIdx.x;
    const int c[NEXP] = {ws[0], ws[1], ws[2], ws[3], ws[4]};
    const int s[NEXP] = {ws[8], ws[9], ws[10], ws[11], ws[12]};

    // equal-work groups (TC*K = 2048 MACs/thread), heavy experts first
    int gb = 0, e = -1, lg = 0, TC = 0;
    #pragma unroll
    for (int j = 0; j < NEXP; ++j) {
        const int ee = 4 - j;
        const int tc = 256 >> ee;                       // 2048 / K
        const int ng = (c[ee] + tc - 1) >> (8 - ee);    // ceil(c/tc)
        if (e < 0 && g < gb + ng) { e = ee; lg = g - gb; TC = tc; }
        gb += ng;
    }
    if (e < 0) return;

    int tcnt = c[e] - lg * TC;
    if (tcnt > TC) tcnt = TC;
    const int o = threadIdx.x;                          // 0..511
    const int* tokp = ws + PERMOFF + s[e] + lg * TC;
    const float bias = b[e * NOUT + o];
    const float* wt2e = wt2 + (size_t)e * 32 * NOUT * 4;

    switch (e) {
        case 0: run_group<8>  (x, wt2e, bias, tokp, tcnt, o, out); break;
        case 1: run_group<16> (x, wt2e, bias, tokp, tcnt, o, out); break;
        case 2: run_group<32> (x, wt2e, bias, tokp, tcnt, o, out); break;
        case 3: run_group<64> (x, wt2e, bias, tokp, tcnt, o, out); break;
        case 4: run_group<128>(x, wt2e, bias, tokp, tcnt, o, out); break;
    }
}

extern "C" void kernel_launch(void* const* d_in, const int* in_sizes, int n_in,
                              void* d_out, int out_size, void* d_ws, size_t ws_size,
                              hipStream_t stream) {
    const float* x    = (const float*)d_in[0];
    const int*   feat = (const int*)d_in[1];
    const float* w    = (const float*)d_in[2];
    const float* b    = (const float*)d_in[3];
    float* out = (float*)d_out;
    int*   ws  = (int*)d_ws;

    const int n  = in_sizes[1];                         // tokens = 32768
    const int nb = (n + 255) / 256;                     // 128 (<= NBMAX)

    const size_t wt2_off = (((size_t)(PERMOFF + n)) * 4 + 255) & ~(size_t)255;
    float* wt2 = (float*)((char*)d_ws + wt2_off);       // 1.31 MB

    misl_prep<<<nb + 320, 256, 0, stream>>>(feat, w, ws, wt2, n, nb);
    misl_scatter<<<nb, 256, 0, stream>>>(feat, ws, n, nb);
    misl_main<<<n / 16 + NEXP, 512, 0, stream>>>(x, wt2, b, ws, out);
}

// Round 5
// 107.001 us; speedup vs baseline: 2.9000x; 2.2496x over previous
//
#include <hip/hip_runtime.h>

#define NEXP 5
#define MAXF 128
#define NOUT 512
#define NBMAX 256
#define PERMOFF (64 + NBMAX * NEXP)   // 1344 ints

typedef __attribute__((ext_vector_type(8))) short short8;
typedef __attribute__((ext_vector_type(4))) float floatx4;

__device__ __forceinline__ ushort f2bf(float f) {   // RNE fp32->bf16
    uint u = __float_as_uint(f);
    u += 0x7FFF + ((u >> 16) & 1);
    return (ushort)(u >> 16);
}

// ws ints: [0..4]=cnt, [8..12]=seg, [64..64+nb*5)=per-block hist partials,
// [PERMOFF..PERMOFF+n)=perm. Then 256B-aligned Wb: bf16[5][4][32][64][8]
// (B-fragment order: [expert][kstep][n/16][lane][j], zero-padded past K).

__global__ __launch_bounds__(256) void misl_prep(
    const int* __restrict__ feat, const float* __restrict__ w,
    int* __restrict__ ws, ushort* __restrict__ wb, int n, int nb) {
    if ((int)blockIdx.x < nb) {
        __shared__ int lcnt[NEXP];
        const int tid = threadIdx.x;
        if (tid < NEXP) lcnt[tid] = 0;
        __syncthreads();
        const int t = blockIdx.x * 256 + tid;
        if (t < n) { const int e = __ffs(feat[t]) - 4; atomicAdd(&lcnt[e], 1); }
        __syncthreads();
        if (tid < NEXP) ws[64 + blockIdx.x * NEXP + tid] = lcnt[tid];
    } else {
        const int idx = ((int)blockIdx.x - nb) * 256 + threadIdx.x;  // 0..40959
        const int lane = idx & 63, nb16 = (idx >> 6) & 31;
        const int s = (idx >> 11) & 3, e = idx >> 13;
        if (e < NEXP) {
            const int ncol = nb16 * 16 + (lane & 15);
            const int k0 = s * 32 + (lane >> 4) * 8;
            const int K = 8 << e;
            const float* wr = w + ((size_t)e * NOUT + ncol) * MAXF + k0;
            short8 v;
            #pragma unroll
            for (int j = 0; j < 8; ++j)
                v[j] = (short)((k0 + j < K) ? f2bf(wr[j]) : (ushort)0);
            *(short8*)(wb + (size_t)idx * 8) = v;
        }
    }
}

__global__ __launch_bounds__(256) void misl_scatter(
    const int* __restrict__ feat, int* __restrict__ ws, int n, int nb) {
    __shared__ int ph[NBMAX * NEXP];
    __shared__ int lcnt[NEXP], lbase[NEXP], ltot[NEXP];
    const int tid = threadIdx.x;
    for (int i = tid; i < nb * NEXP; i += 256) ph[i] = ws[64 + i];
    if (tid < NEXP) lcnt[tid] = 0;
    __syncthreads();
    if (tid < NEXP) {
        int tot = 0, pre = 0;
        for (int bb = 0; bb < nb; ++bb) {
            if (bb == (int)blockIdx.x) pre = tot;
            tot += ph[bb * NEXP + tid];
        }
        ltot[tid] = tot; lbase[tid] = pre;
    }
    __syncthreads();
    if (tid < NEXP) {
        int seg = 0;
        for (int e = 0; e < tid; ++e) seg += ltot[e];
        lbase[tid] += seg;
        if (blockIdx.x == 0) { ws[tid] = ltot[tid]; ws[8 + tid] = seg; }
    }
    __syncthreads();
    const int t = blockIdx.x * 256 + tid;
    if (t < n) {
        const int e = __ffs(feat[t]) - 4;
        const int r = atomicAdd(&lcnt[e], 1);
        ws[PERMOFF + lbase[e] + r] = t;
    }
}

// wave = 16 tokens x 64 outputs via 4 MFMA C-frags; A gathered fp32->bf16,
// B from pre-packed Wb (contiguous 16B/lane), bias pre-loaded into C.
template <int NS>
__device__ __forceinline__ void mfma_group(
    const float* __restrict__ x, const ushort* __restrict__ wbe,
    const float* __restrict__ be, const int* __restrict__ ltok, int tcnt,
    int lane, int n_base, float* __restrict__ out) {
    const int m = lane & 15, q = lane >> 4;
    floatx4 acc[4];
    #pragma unroll
    for (int bi = 0; bi < 4; ++bi) {
        const float bv = be[n_base + bi * 16 + m];
        acc[bi] = floatx4{bv, bv, bv, bv};
    }
    const int tokA = ltok[m];
    const float* xr = x + (size_t)tokA * MAXF + q * 8;
    #pragma unroll
    for (int s = 0; s < NS; ++s) {
        const float4 xa = *(const float4*)(xr + s * 32);
        const float4 xb = *(const float4*)(xr + s * 32 + 4);
        short8 af;
        af[0] = (short)f2bf(xa.x); af[1] = (short)f2bf(xa.y);
        af[2] = (short)f2bf(xa.z); af[3] = (short)f2bf(xa.w);
        af[4] = (short)f2bf(xb.x); af[5] = (short)f2bf(xb.y);
        af[6] = (short)f2bf(xb.z); af[7] = (short)f2bf(xb.w);
        #pragma unroll
        for (int bi = 0; bi < 4; ++bi) {
            const short8 bf = *(const short8*)(
                wbe + ((size_t)(s * 32 + (n_base >> 4) + bi) * 64 + lane) * 8);
            acc[bi] = __builtin_amdgcn_mfma_f32_16x16x32_bf16(af, bf, acc[bi], 0, 0, 0);
        }
    }
    #pragma unroll
    for (int r = 0; r < 4; ++r) {
        const int mi = q * 4 + r;
        if (mi < tcnt) {
            const int tok = ltok[mi];
            float* orow = out + (size_t)tok * NOUT + n_base + m;
            #pragma unroll
            for (int bi = 0; bi < 4; ++bi) orow[bi * 16] = acc[bi][r];
        }
    }
}

__global__ __launch_bounds__(256) void misl_main(
    const float* __restrict__ x, const ushort* __restrict__ wb,
    const float* __restrict__ b, const int* __restrict__ ws,
    float* __restrict__ out) {
    const int g = blockIdx.x >> 1;
    const int half = blockIdx.x & 1;
    const int c[NEXP] = {ws[0], ws[1], ws[2], ws[3], ws[4]};
    const int sg[NEXP] = {ws[8], ws[9], ws[10], ws[11], ws[12]};

    int gb = 0, e = -1, lg = 0;               // heavy experts first
    #pragma unroll
    for (int j = 0; j < NEXP; ++j) {
        const int ee = 4 - j;
        const int ng = (c[ee] + 15) >> 4;
        if (e < 0 && g < gb + ng) { e = ee; lg = g - gb; }
        gb += ng;
    }
    if (e < 0) return;

    int tcnt = c[e] - lg * 16;
    if (tcnt > 16) tcnt = 16;

    __shared__ int ltok[16];
    if (threadIdx.x < 16) {
        const int ti = ((int)threadIdx.x < tcnt) ? (int)threadIdx.x : tcnt - 1;
        ltok[threadIdx.x] = ws[PERMOFF + sg[e] + lg * 16 + ti];
    }
    __syncthreads();

    const int lane = threadIdx.x & 63;
    const int wave = __builtin_amdgcn_readfirstlane(threadIdx.x >> 6);
    const int n_base = half * 256 + wave * 64;
    const ushort* wbe = wb + (size_t)e * 4 * 32 * 64 * 8;
    const float* be = b + e * NOUT;

    switch (e) {
        case 0: mfma_group<1>(x, wbe, be, ltok, tcnt, lane, n_base, out); break;
        case 1: mfma_group<1>(x, wbe, be, ltok, tcnt, lane, n_base, out); break;
        case 2: mfma_group<1>(x, wbe, be, ltok, tcnt, lane, n_base, out); break;
        case 3: mfma_group<2>(x, wbe, be, ltok, tcnt, lane, n_base, out); break;
        case 4: mfma_group<4>(x, wbe, be, ltok, tcnt, lane, n_base, out); break;
    }
}

extern "C" void kernel_launch(void* const* d_in, const int* in_sizes, int n_in,
                              void* d_out, int out_size, void* d_ws, size_t ws_size,
                              hipStream_t stream) {
    const float* x    = (const float*)d_in[0];
    const int*   feat = (const int*)d_in[1];
    const float* w    = (const float*)d_in[2];
    const float* b    = (const float*)d_in[3];
    float* out = (float*)d_out;
    int*   ws  = (int*)d_ws;

    const int n  = in_sizes[1];                   // tokens = 32768
    const int nb = (n + 255) / 256;               // 128

    const size_t wb_off = (((size_t)(PERMOFF + n)) * 4 + 255) & ~(size_t)255;
    ushort* wb = (ushort*)((char*)d_ws + wb_off); // 655 KB (bf16 B-frag pack)

    misl_prep<<<nb + 160, 256, 0, stream>>>(feat, w, ws, wb, n, nb);
    misl_scatter<<<nb, 256, 0, stream>>>(feat, ws, n, nb);
    misl_main<<<(n / 16 + NEXP) * 2, 256, 0, stream>>>(x, wb, b, ws, out);
}

// Round 6
// 100.005 us; speedup vs baseline: 3.1029x; 1.0700x over previous
//
#include <hip/hip_runtime.h>

#define NEXP 5
#define MAXF 128
#define NOUT 512
#define NBMAX 256
#define PERMOFF (64 + NBMAX * NEXP)   // 1344 ints

typedef __attribute__((ext_vector_type(8))) short short8;
typedef __attribute__((ext_vector_type(4))) float floatx4;

__device__ __forceinline__ ushort f2bf(float f) {   // RNE fp32->bf16
    uint u = __float_as_uint(f);
    u += 0x7FFF + ((u >> 16) & 1);
    return (ushort)(u >> 16);
}

// ws ints: [0..4]=cnt, [8..12]=seg, [64..64+nb*5)=per-block hist partials,
// [PERMOFF..PERMOFF+n)=perm.
// Then 256B-aligned: Wb bf16[5][4][32][64][8] (B-frag order, zero-padded past K),
// then xb bf16[n][128] (x rounded to bf16).

__global__ __launch_bounds__(256) void misl_hist(
    const int* __restrict__ feat, int* __restrict__ ws, int n) {
    __shared__ int lcnt[NEXP];
    const int tid = threadIdx.x;
    if (tid < NEXP) lcnt[tid] = 0;
    __syncthreads();
    const int t = blockIdx.x * 256 + tid;
    if (t < n) { const int e = __ffs(feat[t]) - 4; atomicAdd(&lcnt[e], 1); }
    __syncthreads();
    if (tid < NEXP) ws[64 + blockIdx.x * NEXP + tid] = lcnt[tid];
}

// blocks [0,nb): scatter; [nb,nb+160): W pack; rest: x fp32->bf16 convert.
__global__ __launch_bounds__(256) void misl_rest(
    const int* __restrict__ feat, const float* __restrict__ x,
    const float* __restrict__ w, int* __restrict__ ws,
    ushort* __restrict__ wb, ushort* __restrict__ xb, int n, int nb) {
    const int tid = threadIdx.x;
    if ((int)blockIdx.x < nb) {
        __shared__ int ph[NBMAX * NEXP];
        __shared__ int lcnt[NEXP], lbase[NEXP], ltot[NEXP];
        for (int i = tid; i < nb * NEXP; i += 256) ph[i] = ws[64 + i];
        if (tid < NEXP) lcnt[tid] = 0;
        __syncthreads();
        if (tid < NEXP) {
            int tot = 0, pre = 0;
            for (int bb = 0; bb < nb; ++bb) {
                if (bb == (int)blockIdx.x) pre = tot;
                tot += ph[bb * NEXP + tid];
            }
            ltot[tid] = tot; lbase[tid] = pre;
        }
        __syncthreads();
        if (tid < NEXP) {
            int seg = 0;
            for (int e = 0; e < tid; ++e) seg += ltot[e];
            lbase[tid] += seg;
            if (blockIdx.x == 0) { ws[tid] = ltot[tid]; ws[8 + tid] = seg; }
        }
        __syncthreads();
        const int t = blockIdx.x * 256 + tid;
        if (t < n) {
            const int e = __ffs(feat[t]) - 4;
            const int r = atomicAdd(&lcnt[e], 1);
            ws[PERMOFF + lbase[e] + r] = t;
        }
    } else if ((int)blockIdx.x < nb + 160) {
        const int idx = ((int)blockIdx.x - nb) * 256 + tid;  // 0..40959
        const int lane = idx & 63, nb16 = (idx >> 6) & 31;
        const int s = (idx >> 11) & 3, e = idx >> 13;
        if (e < NEXP) {
            const int ncol = nb16 * 16 + (lane & 15);
            const int k0 = s * 32 + (lane >> 4) * 8;
            const int K = 8 << e;
            const float* wr = w + ((size_t)e * NOUT + ncol) * MAXF + k0;
            short8 v;
            #pragma unroll
            for (int j = 0; j < 8; ++j)
                v[j] = (short)((k0 + j < K) ? f2bf(wr[j]) : (ushort)0);
            *(short8*)(wb + (size_t)idx * 8) = v;
        }
    } else {
        const int idx = ((int)blockIdx.x - nb - 160) * 256 + tid;  // n*16 total
        if (idx < n * 16) {
            const float4 a = *(const float4*)(x + (size_t)idx * 8);
            const float4 c = *(const float4*)(x + (size_t)idx * 8 + 4);
            short8 v;
            v[0] = (short)f2bf(a.x); v[1] = (short)f2bf(a.y);
            v[2] = (short)f2bf(a.z); v[3] = (short)f2bf(a.w);
            v[4] = (short)f2bf(c.x); v[5] = (short)f2bf(c.y);
            v[6] = (short)f2bf(c.z); v[7] = (short)f2bf(c.w);
            *(short8*)(xb + (size_t)idx * 8) = v;
        }
    }
}

// wave = 16 tokens x 64 cols per group; 4 groups/block; B frags + bias hoisted.
template <int NS>
__device__ __forceinline__ void mfma_run(
    const ushort* __restrict__ xb, const ushort* __restrict__ wbe,
    const float* __restrict__ be, const int* __restrict__ tokp, int rem,
    int lane, int n_base, float* __restrict__ out) {
    const int m = lane & 15, q = lane >> 4;
    const int nb16 = n_base >> 4;
    short8 bf[NS][4];
    #pragma unroll
    for (int s = 0; s < NS; ++s)
        #pragma unroll
        for (int bi = 0; bi < 4; ++bi)
            bf[s][bi] = *(const short8*)(wbe + ((size_t)((s * 32 + nb16 + bi)) * 64 + lane) * 8);
    float bv[4];
    #pragma unroll
    for (int bi = 0; bi < 4; ++bi) bv[bi] = be[n_base + bi * 16 + m];

    const int trips = (rem + 15) >> 4;          // <= 4
    for (int g = 0; g < trips; ++g) {
        const int base = g * 16;
        const int lim = rem - base;             // >= 1
        const int idx = (m < lim) ? m : lim - 1;
        const int tokv = tokp[base + idx];
        const ushort* xr = xb + (size_t)tokv * MAXF + q * 8;
        floatx4 acc[4];
        #pragma unroll
        for (int bi = 0; bi < 4; ++bi)
            acc[bi] = floatx4{bv[bi], bv[bi], bv[bi], bv[bi]};
        #pragma unroll
        for (int s = 0; s < NS; ++s) {
            const short8 af = *(const short8*)(xr + s * 32);
            #pragma unroll
            for (int bi = 0; bi < 4; ++bi)
                acc[bi] = __builtin_amdgcn_mfma_f32_16x16x32_bf16(af, bf[s][bi], acc[bi], 0, 0, 0);
        }
        #pragma unroll
        for (int r = 0; r < 4; ++r) {
            const int mi = q * 4 + r;
            const int tr = __shfl(tokv, mi, 16);    // token of row mi
            if (mi < lim) {
                float* orow = out + (size_t)tr * NOUT + n_base + m;
                #pragma unroll
                for (int bi = 0; bi < 4; ++bi) orow[bi * 16] = acc[bi][r];
            }
        }
    }
}

__global__ __launch_bounds__(256) void misl_main(
    const ushort* __restrict__ xb, const ushort* __restrict__ wb,
    const float* __restrict__ b, const int* __restrict__ ws,
    float* __restrict__ out) {
    const int g = blockIdx.x >> 1;
    const int half = blockIdx.x & 1;
    const int c[NEXP] = {ws[0], ws[1], ws[2], ws[3], ws[4]};
    const int sg[NEXP] = {ws[8], ws[9], ws[10], ws[11], ws[12]};

    int gb = 0, e = -1, lgs = 0;                // heavy experts first, 64 tok/block
    #pragma unroll
    for (int j = 0; j < NEXP; ++j) {
        const int ee = 4 - j;
        const int ng = (c[ee] + 63) >> 6;
        if (e < 0 && g < gb + ng) { e = ee; lgs = g - gb; }
        gb += ng;
    }
    if (e < 0) return;

    int rem = c[e] - lgs * 64;
    if (rem > 64) rem = 64;
    const int* tokp = ws + PERMOFF + sg[e] + lgs * 64;
    const int lane = threadIdx.x & 63;
    const int wave = threadIdx.x >> 6;
    const int n_base = half * 256 + wave * 64;
    const ushort* wbe = wb + (size_t)e * 4 * 32 * 64 * 8;
    const float* be = b + e * NOUT;

    switch (e) {
        case 0: mfma_run<1>(xb, wbe, be, tokp, rem, lane, n_base, out); break;
        case 1: mfma_run<1>(xb, wbe, be, tokp, rem, lane, n_base, out); break;
        case 2: mfma_run<1>(xb, wbe, be, tokp, rem, lane, n_base, out); break;
        case 3: mfma_run<2>(xb, wbe, be, tokp, rem, lane, n_base, out); break;
        case 4: mfma_run<4>(xb, wbe, be, tokp, rem, lane, n_base, out); break;
    }
}

extern "C" void kernel_launch(void* const* d_in, const int* in_sizes, int n_in,
                              void* d_out, int out_size, void* d_ws, size_t ws_size,
                              hipStream_t stream) {
    const float* x    = (const float*)d_in[0];
    const int*   feat = (const int*)d_in[1];
    const float* w    = (const float*)d_in[2];
    const float* b    = (const float*)d_in[3];
    float* out = (float*)d_out;
    int*   ws  = (int*)d_ws;

    const int n  = in_sizes[1];                   // tokens = 32768
    const int nb = (n + 255) / 256;               // 128

    const size_t wb_off = (((size_t)(PERMOFF + n)) * 4 + 255) & ~(size_t)255;
    ushort* wb = (ushort*)((char*)d_ws + wb_off);             // 655 KB
    const size_t xb_off = (wb_off + (size_t)NEXP * 4 * 32 * 64 * 8 * 2 + 255) & ~(size_t)255;
    ushort* xb = (ushort*)((char*)d_ws + xb_off);             // n*256 B = 8.4 MB

    misl_hist<<<nb, 256, 0, stream>>>(feat, ws, n);
    const int cvb = (n * 16 + 255) / 256;                     // 2048
    misl_rest<<<nb + 160 + cvb, 256, 0, stream>>>(feat, x, w, ws, wb, xb, n, nb);
    misl_main<<<((n + 63) / 64 + NEXP) * 2, 256, 0, stream>>>(xb, wb, b, ws, out);
}

// Round 7
// 96.774 us; speedup vs baseline: 3.2065x; 1.0334x over previous
//
#include <hip/hip_runtime.h>

#define NEXP 5
#define MAXF 128
#define NOUT 512
#define PERMOFF 64

typedef __attribute__((ext_vector_type(8))) short short8;
typedef __attribute__((ext_vector_type(4))) float floatx4;

__device__ __forceinline__ ushort f2bf(float f) {   // RNE fp32->bf16
    uint u = __float_as_uint(f);
    u += 0x7FFF + ((u >> 16) & 1);
    return (ushort)(u >> 16);
}

// ws ints: [8..12] = per-expert scatter cursors (== counts when done; memset 0),
// [PERMOFF + e*n + i] = perm (fixed per-expert segment bases, no prefix needed).
// Then 256B-aligned: Wb bf16[5][4][32][64][8] (B-frag order, zero-padded past K),
// then xb bf16[n][128].

// blocks [0,nb): scatter-direct; [nb,nb+160): W pack; rest: x fp32->bf16.
__global__ __launch_bounds__(256) void misl_prep(
    const int* __restrict__ feat, const float* __restrict__ x,
    const float* __restrict__ w, int* __restrict__ ws,
    ushort* __restrict__ wb, ushort* __restrict__ xb, int n, int nb) {
    const int tid = threadIdx.x;
    if ((int)blockIdx.x < nb) {
        __shared__ int lcnt[NEXP], lbase[NEXP];
        if (tid < NEXP) lcnt[tid] = 0;
        __syncthreads();
        const int t = blockIdx.x * 256 + tid;
        int e = 0, r = 0;
        if (t < n) {
            e = __ffs(feat[t]) - 4;     // 8->0,16->1,32->2,64->3,128->4
            r = atomicAdd(&lcnt[e], 1);
        }
        __syncthreads();
        if (tid < NEXP) lbase[tid] = atomicAdd(&ws[8 + tid], lcnt[tid]);
        __syncthreads();
        if (t < n) ws[PERMOFF + e * n + lbase[e] + r] = t;
    } else if ((int)blockIdx.x < nb + 160) {
        const int idx = ((int)blockIdx.x - nb) * 256 + tid;  // 0..40959
        const int lane = idx & 63, nb16 = (idx >> 6) & 31;
        const int s = (idx >> 11) & 3, e = idx >> 13;
        if (e < NEXP) {
            const int ncol = nb16 * 16 + (lane & 15);
            const int k0 = s * 32 + (lane >> 4) * 8;
            const int K = 8 << e;
            const float* wr = w + ((size_t)e * NOUT + ncol) * MAXF + k0;
            short8 v;
            #pragma unroll
            for (int j = 0; j < 8; ++j)
                v[j] = (short)((k0 + j < K) ? f2bf(wr[j]) : (ushort)0);
            *(short8*)(wb + (size_t)idx * 8) = v;
        }
    } else {
        const int idx = ((int)blockIdx.x - nb - 160) * 256 + tid;  // n*16 total
        if (idx < n * 16) {
            const float4 a = *(const float4*)(x + (size_t)idx * 8);
            const float4 c = *(const float4*)(x + (size_t)idx * 8 + 4);
            short8 v;
            v[0] = (short)f2bf(a.x); v[1] = (short)f2bf(a.y);
            v[2] = (short)f2bf(a.z); v[3] = (short)f2bf(a.w);
            v[4] = (short)f2bf(c.x); v[5] = (short)f2bf(c.y);
            v[6] = (short)f2bf(c.z); v[7] = (short)f2bf(c.w);
            *(short8*)(xb + (size_t)idx * 8) = v;
        }
    }
}

// wave = 16 tokens x 64 cols; 8 waves/block -> 64 tokens x 512 cols per block.
// B frags + bias hoisted per wave; x rows read once per 64-token group.
template <int NS>
__device__ __forceinline__ void mfma_run(
    const ushort* __restrict__ xb, const ushort* __restrict__ wbe,
    const float* __restrict__ be, const int* __restrict__ tokp, int rem,
    int lane, int n_base, float* __restrict__ out) {
    const int m = lane & 15, q = lane >> 4;
    const int nb16 = n_base >> 4;
    short8 bf[NS][4];
    #pragma unroll
    for (int s = 0; s < NS; ++s)
        #pragma unroll
        for (int bi = 0; bi < 4; ++bi)
            bf[s][bi] = *(const short8*)(wbe + ((size_t)(s * 32 + nb16 + bi) * 64 + lane) * 8);
    float bv[4];
    #pragma unroll
    for (int bi = 0; bi < 4; ++bi) bv[bi] = be[n_base + bi * 16 + m];

    const int trips = (rem + 15) >> 4;          // <= 4
    for (int g = 0; g < trips; ++g) {
        const int base = g * 16;
        const int lim = rem - base;             // >= 1
        const int idx = (m < lim) ? m : lim - 1;
        const int tokv = tokp[base + idx];
        const ushort* xr = xb + (size_t)tokv * MAXF + q * 8;
        floatx4 acc[4];
        #pragma unroll
        for (int bi = 0; bi < 4; ++bi)
            acc[bi] = floatx4{bv[bi], bv[bi], bv[bi], bv[bi]};
        #pragma unroll
        for (int s = 0; s < NS; ++s) {
            const short8 af = *(const short8*)(xr + s * 32);
            #pragma unroll
            for (int bi = 0; bi < 4; ++bi)
                acc[bi] = __builtin_amdgcn_mfma_f32_16x16x32_bf16(af, bf[s][bi], acc[bi], 0, 0, 0);
        }
        #pragma unroll
        for (int r = 0; r < 4; ++r) {
            const int mi = q * 4 + r;
            const int tr = __shfl(tokv, mi, 16);    // token of row mi
            if (mi < lim) {
                float* orow = out + (size_t)tr * NOUT + n_base + m;
                #pragma unroll
                for (int bi = 0; bi < 4; ++bi) orow[bi * 16] = acc[bi][r];
            }
        }
    }
}

__global__ __launch_bounds__(512) void misl_main(
    const ushort* __restrict__ xb, const ushort* __restrict__ wb,
    const float* __restrict__ b, const int* __restrict__ ws,
    float* __restrict__ out, int n) {
    const int g = blockIdx.x;
    const int c[NEXP] = {ws[8], ws[9], ws[10], ws[11], ws[12]};

    int gb = 0, e = -1, lgs = 0;                // heavy experts first
    #pragma unroll
    for (int j = 0; j < NEXP; ++j) {
        const int ee = 4 - j;
        const int ng = (c[ee] + 63) >> 6;
        if (e < 0 && g < gb + ng) { e = ee; lgs = g - gb; }
        gb += ng;
    }
    if (e < 0) return;

    int rem = c[e] - lgs * 64;
    if (rem > 64) rem = 64;
    const int* tokp = ws + PERMOFF + e * n + lgs * 64;
    const int lane = threadIdx.x & 63;
    const int wave = threadIdx.x >> 6;          // 0..7
    const int n_base = wave * 64;
    const ushort* wbe = wb + (size_t)e * 4 * 32 * 64 * 8;
    const float* be = b + e * NOUT;

    switch (e) {
        case 0: mfma_run<1>(xb, wbe, be, tokp, rem, lane, n_base, out); break;
        case 1: mfma_run<1>(xb, wbe, be, tokp, rem, lane, n_base, out); break;
        case 2: mfma_run<1>(xb, wbe, be, tokp, rem, lane, n_base, out); break;
        case 3: mfma_run<2>(xb, wbe, be, tokp, rem, lane, n_base, out); break;
        case 4: mfma_run<4>(xb, wbe, be, tokp, rem, lane, n_base, out); break;
    }
}

extern "C" void kernel_launch(void* const* d_in, const int* in_sizes, int n_in,
                              void* d_out, int out_size, void* d_ws, size_t ws_size,
                              hipStream_t stream) {
    const float* x    = (const float*)d_in[0];
    const int*   feat = (const int*)d_in[1];
    const float* w    = (const float*)d_in[2];
    const float* b    = (const float*)d_in[3];
    float* out = (float*)d_out;
    int*   ws  = (int*)d_ws;

    const int n  = in_sizes[1];                   // tokens = 32768
    const int nb = (n + 255) / 256;               // 128

    const size_t wb_off = (((size_t)(PERMOFF + (size_t)NEXP * n) * 4) + 255) & ~(size_t)255;
    ushort* wb = (ushort*)((char*)d_ws + wb_off);             // 655 KB
    const size_t xb_off = (wb_off + (size_t)NEXP * 4 * 32 * 64 * 8 * 2 + 255) & ~(size_t)255;
    ushort* xb = (ushort*)((char*)d_ws + xb_off);             // 8.4 MB

    hipMemsetAsync(ws, 0, 64 * sizeof(int), stream);          // zero cursors
    const int cvb = (n * 16 + 255) / 256;                     // 2048
    misl_prep<<<nb + 160 + cvb, 256, 0, stream>>>(feat, x, w, ws, wb, xb, n, nb);
    misl_main<<<(n + 63) / 64 + NEXP, 512, 0, stream>>>(xb, wb, b, ws, out, n);
}